// Round 7
// baseline (344.244 us; speedup 1.0000x reference)
//
#include <hip/hip_runtime.h>

#define NN 50000
#define NPGc 100
#define NG 500
#define DEG 32
#define HC 128
#define HID 64

__device__ __forceinline__ float lrelu(float x) { return x > 0.0f ? x : 0.2f * x; }

// ---- prep: Wa[K][4] = [ W@as_h0 | W@as_h1 | W@ad_h0 | W@ad_h1 ] for both layers ----
__global__ void k_prep(const float* __restrict__ W1, const float* __restrict__ as1,
                       const float* __restrict__ ad1, float* __restrict__ Wa1,
                       const float* __restrict__ W2, const float* __restrict__ as2,
                       const float* __restrict__ ad2, float* __restrict__ Wa2) {
  const float* W  = blockIdx.x ? W2 : W1;
  const float* as_ = blockIdx.x ? as2 : as1;
  const float* ad_ = blockIdx.x ? ad2 : ad1;
  float* Wa = blockIdx.x ? Wa2 : Wa1;
  int K = blockIdx.x ? 64 : 100;
  int t = threadIdx.x;
  for (int u = t; u < K * 4; u += blockDim.x) {
    int k = u >> 2, s = u & 3;
    const float* a = (s < 2) ? as_ : ad_;
    int h = s & 1;
    float acc = 0.f;
    for (int c = 0; c < 64; ++c) acc += W[k * 128 + h * 64 + c] * a[h * 64 + c];
    Wa[k * 4 + s] = acc;
  }
}

// ---- fused layer: per-(graph,head) block. BN-fold -> in-GEMM (64 cols) ->
//      scores -> edge softmax -> aggregation -> gout. xin LDS overlaid after GEMM.
template <int K, bool BN>
__global__ __launch_bounds__(256) void k_layer(
    const float* __restrict__ in, const float* __restrict__ W,
    const float* __restrict__ Wa, const float* __restrict__ AB,
    const int* __restrict__ esrc, const float* __restrict__ bg,
    float* __restrict__ gout) {
  constexpr int KP = (K % 32 == 0) ? K + 4 : K;          // 100 -> 100, 64 -> 68
  __shared__ __align__(16) float xph[NPGc * 64];         // 25.6 KB, this head's xp cols
  __shared__ __align__(16) char ubuf[NPGc * KP * 4];     // phase A/B: xin ; C-E: srcl|sc|alpha
  float* xin = (float*)ubuf;
  unsigned short* srcl = (unsigned short*)ubuf;          // 3200 u16 = 6400 B
  float* sc = (float*)(ubuf + 6400);                     // ssrc_h[100] | sdst_h[100] = 800 B
  float* alpha = (float*)(ubuf + 7232);                  // 100 * 34 floats = 13600 B (tot 20832 <= 27200)

  int t = threadIdx.x;
  int g = blockIdx.x >> 1, h = blockIdx.x & 1;
  int base = g * NPGc;

  // phase A: stage input tile (BN-folded for layer 2)
  constexpr int RQ = K / 4;
  for (int u = t; u < NPGc * RQ; u += 256) {
    int r = u / RQ, q = u % RQ;
    float4 v = ((const float4*)(in + (size_t)(base + r) * K))[q];
    if (BN) {
      float4 a4 = ((const float4*)AB)[q];
      float4 b4 = ((const float4*)(AB + 64))[q];
      v.x = v.x * a4.x + b4.x; v.y = v.y * a4.y + b4.y;
      v.z = v.z * a4.z + b4.z; v.w = v.w * a4.w + b4.w;
    }
    ((float4*)(xin + r * KP))[q] = v;
  }
  __syncthreads();

  // phase B: xph = xin @ W[:, h*64 .. h*64+63]  (W half = 25.6 KB, L1-resident)
  int ng = t >> 4, cg = t & 15;   // 16 node-groups x 16 col-f4
  {
    float4 acc[7];
#pragma unroll
    for (int i = 0; i < 7; ++i) acc[i] = make_float4(0.f, 0.f, 0.f, 0.f);
    const float4* W4 = (const float4*)W;
    float4 w4 = W4[h * 16 + cg];
    for (int k = 0; k < K; ++k) {
      float4 wc = w4;
      if (k + 1 < K) w4 = W4[(k + 1) * 32 + h * 16 + cg];
#pragma unroll
      for (int i = 0; i < 7; ++i) {
        int r = ng + 16 * i;
        if (r < NPGc) {
          float a = xin[r * KP + k];
          acc[i].x += a * wc.x; acc[i].y += a * wc.y;
          acc[i].z += a * wc.z; acc[i].w += a * wc.w;
        }
      }
    }
#pragma unroll
    for (int i = 0; i < 7; ++i) {
      int r = ng + 16 * i;
      if (r < NPGc) ((float4*)xph)[r * 16 + cg] = acc[i];
    }
  }
  // scores into registers (sc LDS still holds xin!)
  float myscore = 0.f;
  if (t < 200) {
    int node = t >> 1, s = t & 1;
    for (int k = 0; k < K; ++k) myscore += xin[node * KP + k] * Wa[k * 4 + s * 2 + h];
  }
  __syncthreads();   // all xin reads done; ubuf is reusable

  // phase C: spill scores, load local src ids
  if (t < 200) sc[(t & 1) * NPGc + (t >> 1)] = myscore;
  for (int u = t; u < NPGc * DEG; u += 256)
    srcl[u] = (unsigned short)(esrc[base * DEG + u] - base);
  __syncthreads();

  // phase D: edge softmax per dst (33 entries incl self-loop)
  if (t < NPGc) {
    float sd = sc[NPGc + t];
    float es = lrelu(sc[t] + sd);
    float m = es;
    float e[DEG];
#pragma unroll
    for (int j = 0; j < DEG; ++j) {
      e[j] = lrelu(sc[srcl[t * DEG + j]] + sd);
      m = fmaxf(m, e[j]);
    }
    float exs = __expf(es - m);
    float den = exs;
#pragma unroll
    for (int j = 0; j < DEG; ++j) { e[j] = __expf(e[j] - m); den += e[j]; }
    float inv = 1.0f / den;
    float* al = alpha + t * (DEG + 2);
#pragma unroll
    for (int j = 0; j < DEG; ++j) al[j] = e[j] * inv;
    al[DEG] = exs * inv;
  }
  __syncthreads();

  // phase E: aggregate + bias -> gout cols [h*64, h*64+64)
  float4 bgv = ((const float4*)bg)[h * 16 + cg];
  for (int d = ng; d < NPGc; d += 16) {
    const float* al = alpha + d * (DEG + 2);
    const unsigned short* sp = srcl + d * DEG;
    float aself = al[DEG];
    float4 x4 = ((float4*)xph)[d * 16 + cg];
    float4 acc;
    acc.x = aself * x4.x; acc.y = aself * x4.y;
    acc.z = aself * x4.z; acc.w = aself * x4.w;
#pragma unroll 8
    for (int j = 0; j < DEG; ++j) {
      float a = al[j];
      float4 v = ((float4*)xph)[(int)sp[j] * 16 + cg];
      acc.x += a * v.x; acc.y += a * v.y;
      acc.z += a * v.z; acc.w += a * v.w;
    }
    acc.x += bgv.x; acc.y += bgv.y; acc.z += bgv.z; acc.w += bgv.w;
    ((float4*)gout)[(size_t)(base + d) * 32 + h * 16 + cg] = acc;
  }
}

// ---- out-GEMM: h = lrelu(g@lW + lb); lW streamed (L1-resident 32 KB) ----
__global__ __launch_bounds__(256) void k_out_gemm(
    const float* __restrict__ gin, const float* __restrict__ lW,
    const float* __restrict__ lb, float* __restrict__ h,
    float* __restrict__ partial) {
  __shared__ __align__(16) float gl[64 * 132];           // 33.8 KB
  __shared__ float psum[2 * HID];
  int t = threadIdx.x;
  int n0 = blockIdx.x * 64;

  for (int u = t; u < 64 * 32; u += 256) {
    int r = u >> 5, q = u & 31;
    int n = n0 + r;
    float4 v = make_float4(0.f, 0.f, 0.f, 0.f);
    if (n < NN) v = ((const float4*)(gin + (size_t)n * HC))[q];
    ((float4*)(gl + r * 132))[q] = v;
  }
  if (t < 2 * HID) psum[t] = 0.f;
  __syncthreads();

  int ng = t >> 4, cg = t & 15;   // 16 node-groups x 16 col-groups(float4)
  int r0 = ng * 4;
  float4 acc[4];
#pragma unroll
  for (int i = 0; i < 4; ++i) acc[i] = make_float4(0.f, 0.f, 0.f, 0.f);

  const float4* lW4 = (const float4*)lW;
  float4 w4 = lW4[cg];
  for (int k = 0; k < HC; ++k) {
    float4 wc = w4;
    if (k + 1 < HC) w4 = lW4[(k + 1) * 16 + cg];
#pragma unroll
    for (int i = 0; i < 4; ++i) {
      float a = gl[(r0 + i) * 132 + k];
      acc[i].x += a * wc.x; acc[i].y += a * wc.y;
      acc[i].z += a * wc.z; acc[i].w += a * wc.w;
    }
  }
  float4 bias = ((const float4*)lb)[cg];
  float s0 = 0, s1 = 0, s2 = 0, s3 = 0, q0 = 0, q1 = 0, q2 = 0, q3 = 0;
#pragma unroll
  for (int i = 0; i < 4; ++i) {
    int n = n0 + r0 + i;
    if (n < NN) {
      float4 v;
      v.x = lrelu(acc[i].x + bias.x); v.y = lrelu(acc[i].y + bias.y);
      v.z = lrelu(acc[i].z + bias.z); v.w = lrelu(acc[i].w + bias.w);
      ((float4*)(h + (size_t)n * HID))[cg] = v;
      s0 += v.x; q0 += v.x * v.x; s1 += v.y; q1 += v.y * v.y;
      s2 += v.z; q2 += v.z * v.z; s3 += v.w; q3 += v.w * v.w;
    }
  }
  int c0 = cg * 4;
  atomicAdd(&psum[c0 + 0], s0); atomicAdd(&psum[c0 + 1], s1);
  atomicAdd(&psum[c0 + 2], s2); atomicAdd(&psum[c0 + 3], s3);
  atomicAdd(&psum[HID + c0 + 0], q0); atomicAdd(&psum[HID + c0 + 1], q1);
  atomicAdd(&psum[HID + c0 + 2], q2); atomicAdd(&psum[HID + c0 + 3], q3);
  __syncthreads();
  if (t < 2 * HID) partial[blockIdx.x * 128 + t] = psum[t];
}

// ---- stats: reduce partials -> BN fold coefficients A,B ----
__global__ __launch_bounds__(256) void k_stats(
    const float* __restrict__ partial, int nb, const float* __restrict__ gamma,
    const float* __restrict__ beta, float* __restrict__ AB) {
  __shared__ float red[2][256];
  int c = blockIdx.x, t = threadIdx.x;
  float s = 0.f, sq = 0.f;
  for (int i = t; i < nb; i += 256) {
    s += partial[i * 128 + c];
    sq += partial[i * 128 + 64 + c];
  }
  red[0][t] = s; red[1][t] = sq;
  __syncthreads();
  for (int o = 128; o > 0; o >>= 1) {
    if (t < o) { red[0][t] += red[0][t + o]; red[1][t] += red[1][t + o]; }
    __syncthreads();
  }
  if (t == 0) {
    float mean = red[0][0] / (float)NN;
    float var = red[1][0] / (float)NN - mean * mean;
    float A = gamma[c] * rsqrtf(var + 1e-5f);
    AB[c] = A;
    AB[64 + c] = beta[c] - mean * A;
  }
}

// ---- pool + MLP head: per-graph mean of BN(h2) -> 64 -> 32 -> 2 ----
__global__ __launch_bounds__(64) void k_pool_mlp(
    const float* __restrict__ h2, const float* __restrict__ AB,
    const float* __restrict__ f1W, const float* __restrict__ f1b,
    const float* __restrict__ f2W, const float* __restrict__ f2b,
    const float* __restrict__ f3W, const float* __restrict__ f3b,
    float* __restrict__ out) {
  __shared__ float pp[4 * 64];
  __shared__ float pooled[64];
  __shared__ float z1[64];
  __shared__ float z2[32];
  int g = blockIdx.x, t = threadIdx.x;
  const float4* hb4 = (const float4*)(h2 + (size_t)g * NPGc * HID);
  int rq = t >> 4, c4 = t & 15;
  float4 s4 = make_float4(0.f, 0.f, 0.f, 0.f);
  for (int r = rq; r < NPGc; r += 4) {
    float4 v = hb4[r * 16 + c4];
    s4.x += v.x; s4.y += v.y; s4.z += v.z; s4.w += v.w;
  }
  ((float4*)pp)[rq * 16 + c4] = s4;
  __syncthreads();
  pooled[t] = (pp[t] + pp[64 + t] + pp[128 + t] + pp[192 + t]) * (1.0f / NPGc) * AB[t] + AB[64 + t];
  __syncthreads();
  float a = f1b[t];
  for (int c = 0; c < 64; ++c) a += pooled[c] * f1W[c * 64 + t];
  z1[t] = lrelu(a);
  __syncthreads();
  if (t < 32) {
    float a2 = f2b[t];
    for (int c = 0; c < 64; ++c) a2 += z1[c] * f2W[c * 32 + t];
    z2[t] = lrelu(a2);
  }
  __syncthreads();
  if (t < 2) {
    float a3 = f3b[t];
    for (int c = 0; c < 32; ++c) a3 += z2[c] * f3W[c * 2 + t];
    out[g * 2 + t] = a3;
  }
}

extern "C" void kernel_launch(void* const* d_in, const int* in_sizes, int n_in,
                              void* d_out, int out_size, void* d_ws, size_t ws_size,
                              hipStream_t stream) {
  const float* x   = (const float*)d_in[0];
  const float* W1  = (const float*)d_in[2];
  const float* as1 = (const float*)d_in[3];
  const float* ad1 = (const float*)d_in[4];
  const float* bg1 = (const float*)d_in[5];
  const float* l1W = (const float*)d_in[6];
  const float* l1b = (const float*)d_in[7];
  const float* g1  = (const float*)d_in[8];
  const float* b1  = (const float*)d_in[9];
  const float* W2  = (const float*)d_in[10];
  const float* as2 = (const float*)d_in[11];
  const float* ad2 = (const float*)d_in[12];
  const float* bg2 = (const float*)d_in[13];
  const float* l2W = (const float*)d_in[14];
  const float* l2b = (const float*)d_in[15];
  const float* g2  = (const float*)d_in[16];
  const float* b2  = (const float*)d_in[17];
  const float* f1W = (const float*)d_in[18];
  const float* f1b = (const float*)d_in[19];
  const float* f2W = (const float*)d_in[20];
  const float* f2b = (const float*)d_in[21];
  const float* f3W = (const float*)d_in[22];
  const float* f3b = (const float*)d_in[23];
  const int* esrc  = (const int*)d_in[24];   // row 0 of edge_index
  float* out = (float*)d_out;

  float* ws = (float*)d_ws;
  size_t off = 0;
  auto alloc = [&](size_t nf) { float* p = ws + off; off += (nf + 63) & ~(size_t)63; return p; };
  float* Wa1     = alloc(100 * 4);
  float* Wa2     = alloc(64 * 4);
  float* gout    = alloc((size_t)NN * HC);
  float* hbuf    = alloc((size_t)NN * HID);
  const int NB = (NN + 63) / 64;   // 782
  float* partial = alloc((size_t)NB * 128);
  float* AB1     = alloc(128);
  float* AB2     = alloc(128);
  (void)in_sizes; (void)n_in; (void)out_size; (void)ws_size;

  k_prep<<<2, 256, 0, stream>>>(W1, as1, ad1, Wa1, W2, as2, ad2, Wa2);
  k_layer<100, false><<<NG * 2, 256, 0, stream>>>(x, W1, Wa1, nullptr, esrc, bg1, gout);
  k_out_gemm<<<NB, 256, 0, stream>>>(gout, l1W, l1b, hbuf, partial);
  k_stats<<<64, 256, 0, stream>>>(partial, NB, g1, b1, AB1);
  k_layer<64, true><<<NG * 2, 256, 0, stream>>>(hbuf, W2, Wa2, AB1, esrc, bg2, gout);
  k_out_gemm<<<NB, 256, 0, stream>>>(gout, l2W, l2b, hbuf, partial);
  k_stats<<<64, 256, 0, stream>>>(partial, NB, g2, b2, AB2);
  k_pool_mlp<<<NG, 64, 0, stream>>>(hbuf, AB2, f1W, f1b, f2W, f2b, f3W, f3b, out);
}